// Round 1
// 187.366 us; speedup vs baseline: 1.2673x; 1.2673x over previous
//
#include <hip/hip_runtime.h>

#define NB 1024
#define LL 4096
#define PP 8192
#define FN 4096   // complex FFT length = PP/2 (real-packed Hilbert)

#define PIF 3.14159265358979323846f

__device__ __forceinline__ float2 cadd(float2 a, float2 b){ return make_float2(a.x+b.x, a.y+b.y); }
__device__ __forceinline__ float2 csub(float2 a, float2 b){ return make_float2(a.x-b.x, a.y-b.y); }
__device__ __forceinline__ float2 cmul(float2 a, float2 b){ return make_float2(a.x*b.x - a.y*b.y, a.x*b.y + a.y*b.x); }

// LDS bank swizzle on the float2 index: fold bits [7:4] into [3:0] (bijective,
// fixes the H=1/H=4 stage conflicts and the digit-reversal gather).
__device__ __forceinline__ int SW(int p){ return p ^ ((p >> 4) & 15); }

// base-4 digit reversal of a 12-bit index (6 digits) — the DIF output permutation.
__device__ __forceinline__ int rho(int k){
    return ((k & 3) << 10) | (((k >> 2) & 3) << 8) | (((k >> 4) & 3) << 6)
         | (((k >> 6) & 3) << 4) | (((k >> 8) & 3) << 2) | ((k >> 10) & 3);
}

// ---- forward radix-4 DIF stage, sub-block stride H ----
template<int H>
__device__ __forceinline__ void fwd_r4(float2* buf, int tid){
#pragma unroll
    for (int m = 0; m < FN/4/256; m++){
        int b = tid + m*256;
        int j = b & (H-1);
        int i = ((b & ~(H-1)) << 2) | j;
        int a0 = SW(i), a1 = SW(i+H), a2 = SW(i+2*H), a3 = SW(i+3*H);
        float2 x0 = buf[a0], x1 = buf[a1], x2 = buf[a2], x3 = buf[a3];
        float2 t0 = cadd(x0,x2), t1 = cadd(x1,x3);
        float2 t2 = csub(x0,x2), t3 = csub(x1,x3);
        float2 y0 = cadd(t0,t1);
        float2 y2 = csub(t0,t1);
        float2 y1 = make_float2(t2.x + t3.y, t2.y - t3.x);   // t2 - i*t3
        float2 y3 = make_float2(t2.x - t3.y, t2.y + t3.x);   // t2 + i*t3
        if (H > 1){
            float sn, cn; __sincosf((-PIF/(2.0f*(float)H)) * (float)j, &sn, &cn);
            float2 E  = make_float2(cn, sn);
            float2 E2 = cmul(E,E);
            float2 E3 = cmul(E2,E);
            y1 = cmul(y1,E); y2 = cmul(y2,E2); y3 = cmul(y3,E3);
        }
        buf[a0] = y0; buf[a1] = y1; buf[a2] = y2; buf[a3] = y3;
    }
}

// ---- inverse radix-4 DIT stage (conjugate mirror, unnormalized: 4x per stage) ----
template<int H>
__device__ __forceinline__ void inv_r4(float2* buf, int tid){
#pragma unroll
    for (int m = 0; m < FN/4/256; m++){
        int b = tid + m*256;
        int j = b & (H-1);
        int i = ((b & ~(H-1)) << 2) | j;
        int a0 = SW(i), a1 = SW(i+H), a2 = SW(i+2*H), a3 = SW(i+3*H);
        float2 z0 = buf[a0], z1 = buf[a1], z2 = buf[a2], z3 = buf[a3];
        if (H > 1){
            float sn, cn; __sincosf((PIF/(2.0f*(float)H)) * (float)j, &sn, &cn);
            float2 E  = make_float2(cn, sn);
            float2 E2 = cmul(E,E);
            float2 E3 = cmul(E2,E);
            z1 = cmul(z1,E); z2 = cmul(z2,E2); z3 = cmul(z3,E3);
        }
        float2 s0 = cadd(z0,z2), s1 = cadd(z1,z3);
        float2 s2 = csub(z0,z2), s3 = csub(z1,z3);
        buf[a0] = cadd(s0,s1);
        buf[a2] = csub(s0,s1);
        buf[a1] = make_float2(s2.x - s3.y, s2.y + s3.x);     // s2 + i*s3
        buf[a3] = make_float2(s2.x + s3.y, s2.y - s3.x);     // s2 - i*s3
    }
}

// ---- Hilbert middle step, in DIF-scrambled position space ----
// Input:  buf[SW(rho(k))] = Z[k],  Z = FFT_FN(x[2n] + i*x[2n+1]),  x real length PP.
// Output: buf[SW(rho(k))] = Z'[k] such that the (unnormalized) inverse chain yields
//         z'[n] = Hx[2n] + i*Hx[2n+1]  (Hx = imag part of the analytic signal).
// Z'[k] = (u*conj(W) - v*W) / (2*FN),  W = e^{-i*pi*k/FN},
//   u = Z[k] + conj(Z[FN-k]),  v = Z[k] - conj(Z[FN-k]);   Z'[0] = 0.
__device__ __forceinline__ void hilbert_mid(float2* buf, int tid){
    const float s = 1.0f/(2.0f*(float)FN);
#pragma unroll
    for (int m = 0; m < 8; m++){
        // k-mapping chosen so rho(k) spreads LDS banks across a wave
        int k = ((tid & 31) << 6) | ((tid >> 5) << 3) | m;
        if (k == 0){
            buf[0] = make_float2(0.0f, 0.0f);                 // Z'[0]=0 (rho(0)=0, SW(0)=0)
            int p = SW(2);                                    // rho(2048) = 2, self-paired
            float2 Z = buf[p];
            buf[p] = make_float2(-2.0f*s*Z.y, 2.0f*s*Z.x);
        } else {
            int pk = SW(rho(k));
            int pj = SW(rho(FN - k));
            float2 Zk = buf[pk];
            float2 Zj = buf[pj];
            float ux = Zk.x + Zj.x, uy = Zk.y - Zj.y;         // u = Zk + conj(Zj)
            float vx = Zk.x - Zj.x, vy = Zk.y + Zj.y;         // v = Zk - conj(Zj)
            float sn, cn; __sincosf((PIF/(float)FN) * (float)k, &sn, &cn);  // conj(W)=(cn,sn)
            float2 zk, zj;
            zk.x = s * ((ux*cn - uy*sn) - (vx*cn + vy*sn));
            zk.y = s * ((ux*sn + uy*cn) + (vx*sn - vy*cn));
            // partner: u2 = conj(u), v2 = -conj(v); Z'[FN-k] = s*(v2*conj(W) - u2*W)
            float u2x = ux,  u2y = -uy;
            float v2x = -vx, v2y = vy;
            zj.x = s * ((v2x*cn - v2y*sn) - (u2x*cn + u2y*sn));
            zj.y = s * ((v2x*sn + v2y*cn) + (u2x*sn - u2y*cn));
            buf[pk] = zk;
            buf[pj] = zj;
        }
    }
}

__global__ __launch_bounds__(256, 4) void k_all(
    const float* __restrict__ g_start,
    const float* __restrict__ g_end,
    const float* __restrict__ g_std,
    const float* __restrict__ g_low,
    const float* __restrict__ g_up,
    const int*   __restrict__ g_win,
    const float* __restrict__ g_scale,
    const float* __restrict__ g_noise,
    const float* __restrict__ g_omit,
    const float* __restrict__ g_ppm,
    const float* __restrict__ g_ppmr,
    float* __restrict__ g_out)
{
    __shared__ float2 buf[FN];          // 32 KB exactly -> 4 blocks/CU (VGPR<=128)
    float* bf  = (float*)buf;           // 8192 floats
    // padded cumsum layout: phys(t) = t + t/32 breaks the stride-16 bank conflict
#define CSI(t) ((t) + ((t) >> 5))
    float* cs  = bf;                    // CSI(0..4096) -> 0..4224
    float* tmp = bf + 4226;             // 8 floats (wave partials)
    float* shv = bf + 4234;             // 2 floats

    const int n    = blockIdx.x;
    const int tid  = threadIdx.x;
    const int lane = tid & 63;
    const int wid  = tid >> 6;          // 4 waves / block
    const float st = g_start[n];
    const float en = g_end[n];
    const float sd = g_std[n];
    const float lo = g_low[n];
    const float up = g_up[n];
    const int   w  = g_win[n];
    const float inv_nm1 = 1.0f / (float)(LL - 1);

    // ---- load 16 fp32 noise steps/thread ----
    float v[16];
    {
        const float4* p = (const float4*)(g_noise + (size_t)n * LL) + (size_t)tid * 4;
#pragma unroll
        for (int q = 0; q < 4; q++) {
            float4 t4 = p[q];
            v[4*q+0] = t4.x; v[4*q+1] = t4.y; v[4*q+2] = t4.z; v[4*q+3] = t4.w;
        }
    }
#pragma unroll
    for (int k = 0; k < 16; k++) v[k] = sd * (v[k] - 0.5f);

    // ---- scan #1 (rand = inclusive cumsum): thread-local + wave shuffle + 4-wave combine ----
    float run = 0.0f;
#pragma unroll
    for (int k = 0; k < 16; k++) { run += v[k]; v[k] = run; }
    float ws = run;
#pragma unroll
    for (int off = 1; off < 64; off <<= 1) { float t = __shfl_up(ws, off); if (lane >= off) ws += t; }
    if (lane == 63) tmp[wid] = ws;
    if (tid == 0)   shv[0] = v[0];                 // rand[0]
    __syncthreads();
    float w0 = tmp[0], w1 = tmp[1], w2s = tmp[2], w3 = tmp[3];
    const float rT = w0 + w1 + w2s + w3;           // rand[L-1]
    const float r0 = shv[0];
    float base = (wid > 0 ? w0 : 0.0f) + (wid > 1 ? w1 : 0.0f) + (wid > 2 ? w2s : 0.0f);
    float excl = base + ws - run;                  // exclusive prefix over earlier threads
    __syncthreads();

    // ---- detrend walk, min/max (wave shuffle reduce) ----
    float del[16];
    float mx = -INFINITY, mn = INFINITY;
#pragma unroll
    for (int k = 0; k < 16; k++) {
        int t = tid * 16 + k;
        float d = (excl + v[k]) - (r0 + (rT - r0) * ((float)t * inv_nm1));
        del[k] = d;
        mx = fmaxf(mx, d); mn = fminf(mn, d);
    }
#pragma unroll
    for (int off = 32; off > 0; off >>= 1) {
        mx = fmaxf(mx, __shfl_xor(mx, off));
        mn = fminf(mn, __shfl_xor(mn, off));
    }
    if (lane == 0) { tmp[wid] = mx; tmp[4 + wid] = mn; }
    __syncthreads();
    mx = fmaxf(fmaxf(tmp[0], tmp[1]), fmaxf(tmp[2], tmp[3]));
    mn = fminf(fminf(tmp[4], tmp[5]), fminf(tmp[6], tmp[7]));
    __syncthreads();

    const float qs = fmaxf(1.0f, (mx - mn) / (up - lo));

    // ---- squeeze + reflect + trend -> walk values ----
    float wv[16];
#pragma unroll
    for (int k = 0; k < 16; k++) {
        int t = tid * 16 + k;
        float tr  = st + (en - st) * ((float)t * inv_nm1);
        float ub  = up - tr;
        float lb2 = lo - tr;
        float d = del[k] / qs;
        float over = d - ub;
        d = (over >= 0.0f) ? (ub - over) : d;
        float under = lb2 - d;
        d = (under >= 0.0f) ? (lb2 + under) : d;
        wv[k] = tr + d;
    }

    // ---- scan #2: exclusive cumsum of walk -> cs[CSI(0..LL)] ----
    run = 0.0f;
#pragma unroll
    for (int k = 0; k < 16; k++) { run += wv[k]; wv[k] = run; }
    ws = run;
#pragma unroll
    for (int off = 1; off < 64; off <<= 1) { float t = __shfl_up(ws, off); if (lane >= off) ws += t; }
    if (lane == 63) tmp[wid] = ws;
    __syncthreads();
    w0 = tmp[0]; w1 = tmp[1]; w2s = tmp[2]; w3 = tmp[3];
    const float grand2 = w0 + w1 + w2s + w3;
    base = (wid > 0 ? w0 : 0.0f) + (wid > 1 ? w1 : 0.0f) + (wid > 2 ? w2s : 0.0f);
    float excl2 = base + ws - run;
#pragma unroll
    for (int k = 0; k < 16; k++) {
        int t = tid * 16 + k;
        cs[CSI(t)] = excl2 + ((k == 0) ? 0.0f : wv[k - 1]);
    }
    if (tid == 255) cs[CSI(LL)] = grand2;
    __syncthreads();

    // ---- box smooth (CYCLIC t = tid + 256k: conflict-free cs reads) ----
    const int wh = w / 2;
    const float invw = 1.0f / (float)w;
    float bvals[16];
#pragma unroll
    for (int k = 0; k < 16; k++) {
        int t  = tid + 256 * k;
        int li = t - wh;
        int hi = li + w;
        li = (li < 0) ? 0 : li;
        hi = (hi > LL) ? LL : hi;
        bvals[k] = (cs[CSI(hi)] - cs[CSI(li)]) * invw;
    }
    if (tid == 0)   shv[0] = bvals[0];     // b[0]
    if (tid == 255) shv[1] = bvals[15];    // b[L-1]
    __syncthreads();
    const float b0 = shv[0], bL = shv[1];

    // ---- detrend #2 + absmax-normalize (cyclic t) ----
    float am = 0.0f;
#pragma unroll
    for (int k = 0; k < 16; k++) {
        int t = tid + 256 * k;
        bvals[k] -= b0 + (bL - b0) * ((float)t * inv_nm1);
        am = fmaxf(am, fabsf(bvals[k]));
    }
#pragma unroll
    for (int off = 32; off > 0; off >>= 1) am = fmaxf(am, __shfl_xor(am, off));
    if (lane == 0) tmp[wid] = am;
    __syncthreads();
    float denom = fmaxf(fmaxf(tmp[0], tmp[1]), fmaxf(tmp[2], tmp[3]));
    denom = (denom == 0.0f) ? 1.0f : denom;
    const float fac = g_omit[n] * g_scale[n] / denom;

    // ---- stash bb row at bf[t] (overwrites cs; all cs reads completed pre-barrier) ----
#pragma unroll
    for (int k = 0; k < 16; k++) {
        int t = tid + 256 * k;
        bf[t] = bvals[k] * fac;
    }
    __syncthreads();

    // ---- interp bb ([xlo,xhi] grid, LL pts) onto ppm axis -> registers ----
    const float xlo = g_ppmr[0];
    const float xhi = g_ppmr[1];
    const float posmul = (float)(LL - 1) / (xhi - xlo);
    float val[PP / 256];
#pragma unroll
    for (int m = 0; m < PP / 256; m++) {
        int jj = tid + m * 256;
        float x = g_ppm[jj];
        float re = 0.0f;
        if (x >= xlo && x <= xhi) {
            float pos = (x - xlo) * posmul;
            int idx = (int)floorf(pos);
            idx = (idx < 0) ? 0 : ((idx > LL - 2) ? (LL - 2) : idx);
            float fr = pos - (float)idx;
            float s0 = bf[idx], s1 = bf[idx + 1];
            re = s0 + (s1 - s0) * fr;
        }
        val[m] = re;
    }
    __syncthreads();   // all bb reads complete

    // ---- write REAL planes now (Re(analytic) == x exactly) and pack x into buf ----
    const size_t base1 = (size_t)NB * 2 * PP + (size_t)n * 2 * PP;  // raw
    const size_t base0 = (size_t)n * 2 * PP;                        // flipped
#pragma unroll
    for (int m = 0; m < PP / 256; m++) {
        int jj = tid + m * 256;
        bf[2 * SW(jj >> 1) + (jj & 1)] = val[m];     // buf[p] = (x[2p], x[2p+1]) packed
        g_out[base1 + jj]            = val[m];       // raw real plane
        g_out[base0 + (PP - 1 - jj)] = val[m];       // flipped real plane
    }
    __syncthreads();

    // ================= forward FFT (4096-pt complex, radix-4 DIF x6) ==============
    fwd_r4<1024>(buf, tid); __syncthreads();
    fwd_r4< 256>(buf, tid); __syncthreads();
    fwd_r4<  64>(buf, tid); __syncthreads();
    fwd_r4<  16>(buf, tid); __syncthreads();
    fwd_r4<   4>(buf, tid); __syncthreads();
    fwd_r4<   1>(buf, tid); __syncthreads();

    // ================= Hilbert pair-fix (real unpack + filter + repack + 1/N) =====
    hilbert_mid(buf, tid); __syncthreads();

    // ================= inverse FFT (radix-4 DIT x6, unnormalized) =================
    inv_r4<   1>(buf, tid); __syncthreads();
    inv_r4<   4>(buf, tid); __syncthreads();
    inv_r4<  16>(buf, tid); __syncthreads();
    inv_r4<  64>(buf, tid); __syncthreads();
    inv_r4< 256>(buf, tid); __syncthreads();
    inv_r4<1024>(buf, tid); __syncthreads();

    // ---- write IMAG planes: buf[p] = (Hx[2p], Hx[2p+1]) ----
#pragma unroll
    for (int m = 0; m < FN / 256; m++) {
        int p = tid + m * 256;
        float2 a = buf[SW(p)];
        *(float2*)(g_out + base1 + PP + 2 * p)          = a;                       // raw imag
        *(float2*)(g_out + base0 + 2 * PP - 2 - 2 * p)  = make_float2(a.y, a.x);   // flipped imag
    }
}

extern "C" void kernel_launch(void* const* d_in, const int* in_sizes, int n_in,
                              void* d_out, int out_size, void* d_ws, size_t ws_size,
                              hipStream_t stream)
{
    const float* start = (const float*)d_in[0];
    const float* end_  = (const float*)d_in[1];
    const float* stdv  = (const float*)d_in[2];
    const float* lowb  = (const float*)d_in[3];
    const float* upb   = (const float*)d_in[4];
    const int*   win   = (const int*)d_in[5];
    const float* scl   = (const float*)d_in[6];
    const float* noise = (const float*)d_in[7];
    const float* omit  = (const float*)d_in[8];
    const float* ppm   = (const float*)d_in[9];
    const float* ppmr  = (const float*)d_in[10];
    float* out = (float*)d_out;

    hipLaunchKernelGGL(k_all, dim3(NB), dim3(256), 0, stream,
                       start, end_, stdv, lowb, upb, win, scl, noise, omit,
                       ppm, ppmr, out);
}